// Round 2
// baseline (662.689 us; speedup 1.0000x reference)
//
#include <hip/hip_runtime.h>
#include <hip/hip_bf16.h>

#define N_NODES 100000
#define FIN 128
#define HID 16
#define NCLS 40
#define NEDGE 3200000

// ---------------------------------------------------------------------------
// K1: per-node projections for layer 1 (fp32).
// Block = 256 threads = 8 nodes x 32 cols. cols 0..15 -> xw1 = x @ W1[1];
// cols 16..31 -> xr1 = x @ root1. x rows + combined weight panel staged in LDS.
// ---------------------------------------------------------------------------
__global__ __launch_bounds__(256) void proj1_kernel(
    const float* __restrict__ x, const float* __restrict__ W1,
    const float* __restrict__ root1,
    float* __restrict__ xw1, float* __restrict__ xr1) {
  __shared__ float xs[8][FIN];      // 4 KB
  __shared__ float WL[FIN][32];     // 16 KB: [:,0:16]=W1[1], [:,16:32]=root1

  int node0 = blockIdx.x * 8;  // N_NODES divisible by 8 -> 12500 blocks
  // stage 8 x-rows: 1024 floats = 256 float4, one per thread
  const float4* xv = (const float4*)(x + (size_t)node0 * FIN);
  ((float4*)&xs[0][0])[threadIdx.x] = xv[threadIdx.x];
  // stage weights: 4096 floats, 16 per thread
  for (int t = threadIdx.x; t < FIN * 32; t += 256) {
    int i = t >> 5, c = t & 31;
    WL[i][c] = (c < 16) ? W1[FIN * HID + i * HID + c]   // W1 shape (2,128,16)
                        : root1[i * HID + (c - 16)];    // root1 shape (128,16)
  }
  __syncthreads();

  int local = threadIdx.x >> 5;
  int col = threadIdx.x & 31;
  int node = node0 + local;
  float acc = 0.f;
#pragma unroll
  for (int i = 0; i < FIN; ++i) acc += xs[local][i] * WL[i][col];
  if (col < 16)
    xw1[node * HID + col] = acc;
  else
    xr1[node * HID + (col - 16)] = acc;
}

// ---------------------------------------------------------------------------
// K2: degree (float) via atomics
// ---------------------------------------------------------------------------
__global__ __launch_bounds__(256) void degree_kernel(
    const int* __restrict__ dst, float* __restrict__ deg) {
  int e = blockIdx.x * blockDim.x + threadIdx.x;
  if (e < NEDGE) atomicAdd(&deg[dst[e]], 1.0f);
}

// ---------------------------------------------------------------------------
// K3/K5: scatter-add of 16-dim projected features along edges.
// thread t -> edge e = t/16, channel c = t%16. 16 lanes share one edge:
// coalesced 64B gather, 16-consecutive-address atomics.
// ---------------------------------------------------------------------------
__global__ __launch_bounds__(256) void scatter16_kernel(
    const int* __restrict__ src, const int* __restrict__ dst,
    const float* __restrict__ val, float* __restrict__ agg) {
  int t = blockIdx.x * blockDim.x + threadIdx.x;
  if (t >= NEDGE * HID) return;  // 51.2M < 2^31
  int e = t >> 4;
  int c = t & 15;
  float v = val[src[e] * HID + c];
  atomicAdd(&agg[dst[e] * HID + c], v);
}

// ---------------------------------------------------------------------------
// K4: h = elu(agg/deg + xr1 + b1)
// ---------------------------------------------------------------------------
__global__ __launch_bounds__(256) void hidden_kernel(
    const float* __restrict__ agg, const float* __restrict__ xr1,
    const float* __restrict__ b1, const float* __restrict__ deg,
    float* __restrict__ h) {
  int t = blockIdx.x * blockDim.x + threadIdx.x;
  if (t >= N_NODES * HID) return;
  int n = t >> 4;
  int c = t & 15;
  float d = fmaxf(deg[n], 1.0f);
  float a = agg[t] / d + xr1[t] + b1[c];
  h[t] = (a > 0.f) ? a : expm1f(a);
}

// ---------------------------------------------------------------------------
// K6: out = (agg/deg) @ W2[1] + h @ root2 + b2, log_softmax, fp32 store.
// one thread per node; weights in LDS.
// ---------------------------------------------------------------------------
__global__ __launch_bounds__(256) void out_kernel(
    const float* __restrict__ h, const float* __restrict__ agg,
    const float* __restrict__ deg, const float* __restrict__ W2,
    const float* __restrict__ root2, const float* __restrict__ b2v,
    float* __restrict__ out) {
  __shared__ float Wl[HID * NCLS];
  __shared__ float Rl[HID * NCLS];
  __shared__ float Bl[NCLS];
  for (int i = threadIdx.x; i < HID * NCLS; i += blockDim.x) {
    Wl[i] = W2[HID * NCLS + i];  // W2 shape (2,16,40): kernel index 1 block
    Rl[i] = root2[i];
  }
  if (threadIdx.x < NCLS) Bl[threadIdx.x] = b2v[threadIdx.x];
  __syncthreads();

  int n = blockIdx.x * blockDim.x + threadIdx.x;
  if (n >= N_NODES) return;

  float inv = 1.0f / fmaxf(deg[n], 1.0f);
  float hv[HID], av[HID];
#pragma unroll
  for (int c = 0; c < HID; ++c) {
    hv[c] = h[n * HID + c];
    av[c] = agg[n * HID + c] * inv;
  }
  float logit[NCLS];
#pragma unroll
  for (int j = 0; j < NCLS; ++j) logit[j] = Bl[j];
  for (int c = 0; c < HID; ++c) {
    float hc = hv[c], ac = av[c];
#pragma unroll
    for (int j = 0; j < NCLS; ++j)
      logit[j] += ac * Wl[c * NCLS + j] + hc * Rl[c * NCLS + j];
  }
  float m = -INFINITY;
#pragma unroll
  for (int j = 0; j < NCLS; ++j) m = fmaxf(m, logit[j]);
  float s = 0.f;
#pragma unroll
  for (int j = 0; j < NCLS; ++j) s += expf(logit[j] - m);
  float lse = m + logf(s);
#pragma unroll
  for (int j = 0; j < NCLS; ++j)
    out[(size_t)n * NCLS + j] = logit[j] - lse;
}

extern "C" void kernel_launch(void* const* d_in, const int* in_sizes, int n_in,
                              void* d_out, int out_size, void* d_ws,
                              size_t ws_size, hipStream_t stream) {
  const float* x = (const float*)d_in[0];
  const int* ei = (const int*)d_in[1];  // (2, E): src row then dst row
  const float* W1 = (const float*)d_in[2];
  const float* root1 = (const float*)d_in[3];
  const float* b1 = (const float*)d_in[4];
  const float* W2 = (const float*)d_in[5];
  const float* root2 = (const float*)d_in[6];
  const float* b2v = (const float*)d_in[7];
  float* out = (float*)d_out;

  const int* src = ei;
  const int* dstp = ei + NEDGE;

  // workspace (floats): [deg N][agg 16N][xw1 16N][xr1 16N][h 16N] = 65N = 26 MB
  float* ws = (float*)d_ws;
  float* deg = ws;                  // N
  float* agg = ws + N_NODES;        // 16N (reused for both layers)
  float* xw1 = ws + 17 * N_NODES;   // 16N
  float* xr1 = ws + 33 * N_NODES;   // 16N
  float* h = ws + 49 * N_NODES;     // 16N

  // zero deg + agg (contiguous 17N floats)
  hipMemsetAsync(ws, 0, (size_t)17 * N_NODES * sizeof(float), stream);

  proj1_kernel<<<N_NODES / 8, 256, 0, stream>>>(x, W1, root1, xw1, xr1);
  degree_kernel<<<(NEDGE + 255) / 256, 256, 0, stream>>>(dstp, deg);
  scatter16_kernel<<<(NEDGE * HID) / 256, 256, 0, stream>>>(src, dstp, xw1,
                                                            agg);
  hidden_kernel<<<(N_NODES * HID + 255) / 256, 256, 0, stream>>>(agg, xr1, b1,
                                                                 deg, h);
  // re-zero agg for layer 2
  hipMemsetAsync(agg, 0, (size_t)16 * N_NODES * sizeof(float), stream);
  scatter16_kernel<<<(NEDGE * HID) / 256, 256, 0, stream>>>(src, dstp, h, agg);
  out_kernel<<<(N_NODES + 255) / 256, 256, 0, stream>>>(h, agg, deg, W2, root2,
                                                        b2v, out);
}

// Round 3
// 657.327 us; speedup vs baseline: 1.0082x; 1.0082x over previous
//
#include <hip/hip_runtime.h>
#include <hip/hip_bf16.h>

#define N_NODES 100000
#define FIN 128
#define HID 16
#define NCLS 40
#define NEDGE 3200000
#define NB_SCAN 391  // ceil(100000/256)

// ---------------------------------------------------------------------------
// proj1: per-node projections for layer 1 (fp32).
// Block = 256 threads = 8 nodes x 32 cols. cols 0..15 -> xw1 = x @ W1[1];
// cols 16..31 -> xr1 = x @ root1. x rows + combined weight panel in LDS.
// ---------------------------------------------------------------------------
__global__ __launch_bounds__(256) void proj1_kernel(
    const float* __restrict__ x, const float* __restrict__ W1,
    const float* __restrict__ root1,
    float* __restrict__ xw1, float* __restrict__ xr1) {
  __shared__ float xs[8][FIN];
  __shared__ float WL[FIN][32];

  int node0 = blockIdx.x * 8;
  const float4* xv = (const float4*)(x + (size_t)node0 * FIN);
  ((float4*)&xs[0][0])[threadIdx.x] = xv[threadIdx.x];
  for (int t = threadIdx.x; t < FIN * 32; t += 256) {
    int i = t >> 5, c = t & 31;
    WL[i][c] = (c < 16) ? W1[FIN * HID + i * HID + c]
                        : root1[i * HID + (c - 16)];
  }
  __syncthreads();

  int local = threadIdx.x >> 5;
  int col = threadIdx.x & 31;
  int node = node0 + local;
  float acc = 0.f;
#pragma unroll
  for (int i = 0; i < FIN; ++i) acc += xs[local][i] * WL[i][col];
  if (col < 16)
    xw1[node * HID + col] = acc;
  else
    xr1[node * HID + (col - 16)] = acc;
}

// ---------------------------------------------------------------------------
// CSR build step 1: histogram of dst into cnt (int atomics)
// ---------------------------------------------------------------------------
__global__ __launch_bounds__(256) void hist_kernel(
    const int* __restrict__ dst, int* __restrict__ cnt) {
  int e = blockIdx.x * blockDim.x + threadIdx.x;
  if (e < NEDGE) atomicAdd(&cnt[dst[e]], 1);
}

// ---------------------------------------------------------------------------
// CSR build step 2a: per-block exclusive scan (256 elems), write block sums
// ---------------------------------------------------------------------------
__global__ __launch_bounds__(256) void scanA_kernel(
    const int* __restrict__ cnt, int* __restrict__ rowptr,
    int* __restrict__ bsum) {
  __shared__ int s[256];
  int i = blockIdx.x * 256 + threadIdx.x;
  int v = (i < N_NODES) ? cnt[i] : 0;
  s[threadIdx.x] = v;
  __syncthreads();
  for (int off = 1; off < 256; off <<= 1) {
    int t = (threadIdx.x >= off) ? s[threadIdx.x - off] : 0;
    __syncthreads();
    s[threadIdx.x] += t;
    __syncthreads();
  }
  if (i < N_NODES) rowptr[i] = s[threadIdx.x] - v;  // exclusive
  if (threadIdx.x == 255) bsum[blockIdx.x] = s[255];
}

// ---------------------------------------------------------------------------
// CSR build step 2b: single-block exclusive scan of block sums (NB_SCAN<=512)
// ---------------------------------------------------------------------------
__global__ __launch_bounds__(512) void scanB_kernel(int* __restrict__ bsum) {
  __shared__ int s[512];
  int v = (threadIdx.x < NB_SCAN) ? bsum[threadIdx.x] : 0;
  s[threadIdx.x] = v;
  __syncthreads();
  for (int off = 1; off < 512; off <<= 1) {
    int t = (threadIdx.x >= off) ? s[threadIdx.x - off] : 0;
    __syncthreads();
    s[threadIdx.x] += t;
    __syncthreads();
  }
  if (threadIdx.x < NB_SCAN) bsum[threadIdx.x] = s[threadIdx.x] - v;
}

// ---------------------------------------------------------------------------
// CSR build step 2c: add block offsets; init cursor = rowptr; set rowptr[N]
// ---------------------------------------------------------------------------
__global__ __launch_bounds__(256) void scanC_kernel(
    int* __restrict__ rowptr, int* __restrict__ cursor,
    const int* __restrict__ bsum) {
  int i = blockIdx.x * 256 + threadIdx.x;
  if (i < N_NODES) {
    int r = rowptr[i] + bsum[blockIdx.x];
    rowptr[i] = r;
    cursor[i] = r;
  }
  if (i == 0) rowptr[N_NODES] = NEDGE;
}

// ---------------------------------------------------------------------------
// CSR build step 3: fill column (src) list bucketed by dst
// ---------------------------------------------------------------------------
__global__ __launch_bounds__(256) void fill_kernel(
    const int* __restrict__ src, const int* __restrict__ dst,
    int* __restrict__ cursor, int* __restrict__ col) {
  int e = blockIdx.x * blockDim.x + threadIdx.x;
  if (e < NEDGE) {
    int pos = atomicAdd(&cursor[dst[e]], 1);
    col[pos] = src[e];
  }
}

// ---------------------------------------------------------------------------
// gather1: agg = sum over in-edges of xw1[src]; fused mean + xr1 + b1 + ELU.
// 16 lanes per node (lane = channel); block = 16 nodes.
// ---------------------------------------------------------------------------
__global__ __launch_bounds__(256) void gather1_kernel(
    const int* __restrict__ rowptr, const int* __restrict__ col,
    const float* __restrict__ xw1, const float* __restrict__ xr1,
    const float* __restrict__ b1, float* __restrict__ h) {
  int t = blockIdx.x * 256 + threadIdx.x;
  int n = t >> 4;
  int c = t & 15;
  if (n >= N_NODES) return;
  int beg = rowptr[n], end = rowptr[n + 1];
  float acc = 0.f;
  int j = beg;
  for (; j + 4 <= end; j += 4) {
    int s0 = col[j], s1 = col[j + 1], s2 = col[j + 2], s3 = col[j + 3];
    float v0 = xw1[s0 * HID + c];
    float v1 = xw1[s1 * HID + c];
    float v2 = xw1[s2 * HID + c];
    float v3 = xw1[s3 * HID + c];
    acc += v0 + v1 + v2 + v3;
  }
  for (; j < end; ++j) acc += xw1[col[j] * HID + c];
  float d = fmaxf((float)(end - beg), 1.0f);
  float a = acc / d + xr1[n * HID + c] + b1[c];
  h[n * HID + c] = (a > 0.f) ? a : expm1f(a);
}

// ---------------------------------------------------------------------------
// gather2: agg2 = sum over in-edges of h[src] (plain sum; out_kernel divides)
// ---------------------------------------------------------------------------
__global__ __launch_bounds__(256) void gather2_kernel(
    const int* __restrict__ rowptr, const int* __restrict__ col,
    const float* __restrict__ h, float* __restrict__ agg2) {
  int t = blockIdx.x * 256 + threadIdx.x;
  int n = t >> 4;
  int c = t & 15;
  if (n >= N_NODES) return;
  int beg = rowptr[n], end = rowptr[n + 1];
  float acc = 0.f;
  int j = beg;
  for (; j + 4 <= end; j += 4) {
    int s0 = col[j], s1 = col[j + 1], s2 = col[j + 2], s3 = col[j + 3];
    float v0 = h[s0 * HID + c];
    float v1 = h[s1 * HID + c];
    float v2 = h[s2 * HID + c];
    float v3 = h[s3 * HID + c];
    acc += v0 + v1 + v2 + v3;
  }
  for (; j < end; ++j) acc += h[col[j] * HID + c];
  agg2[n * HID + c] = acc;
}

// ---------------------------------------------------------------------------
// out: (agg2/deg) @ W2[1] + h @ root2 + b2, log_softmax, fp32 store.
// ---------------------------------------------------------------------------
__global__ __launch_bounds__(256) void out_kernel(
    const float* __restrict__ h, const float* __restrict__ agg2,
    const int* __restrict__ rowptr, const float* __restrict__ W2,
    const float* __restrict__ root2, const float* __restrict__ b2v,
    float* __restrict__ out) {
  __shared__ float Wl[HID * NCLS];
  __shared__ float Rl[HID * NCLS];
  __shared__ float Bl[NCLS];
  for (int i = threadIdx.x; i < HID * NCLS; i += blockDim.x) {
    Wl[i] = W2[HID * NCLS + i];
    Rl[i] = root2[i];
  }
  if (threadIdx.x < NCLS) Bl[threadIdx.x] = b2v[threadIdx.x];
  __syncthreads();

  int n = blockIdx.x * blockDim.x + threadIdx.x;
  if (n >= N_NODES) return;

  float inv = 1.0f / fmaxf((float)(rowptr[n + 1] - rowptr[n]), 1.0f);
  float hv[HID], av[HID];
#pragma unroll
  for (int c = 0; c < HID; ++c) {
    hv[c] = h[n * HID + c];
    av[c] = agg2[n * HID + c] * inv;
  }
  float logit[NCLS];
#pragma unroll
  for (int j = 0; j < NCLS; ++j) logit[j] = Bl[j];
  for (int c = 0; c < HID; ++c) {
    float hc = hv[c], ac = av[c];
#pragma unroll
    for (int j = 0; j < NCLS; ++j)
      logit[j] += ac * Wl[c * NCLS + j] + hc * Rl[c * NCLS + j];
  }
  float m = -INFINITY;
#pragma unroll
  for (int j = 0; j < NCLS; ++j) m = fmaxf(m, logit[j]);
  float s = 0.f;
#pragma unroll
  for (int j = 0; j < NCLS; ++j) s += expf(logit[j] - m);
  float lse = m + logf(s);
#pragma unroll
  for (int j = 0; j < NCLS; ++j)
    out[(size_t)n * NCLS + j] = logit[j] - lse;
}

extern "C" void kernel_launch(void* const* d_in, const int* in_sizes, int n_in,
                              void* d_out, int out_size, void* d_ws,
                              size_t ws_size, hipStream_t stream) {
  const float* x = (const float*)d_in[0];
  const int* ei = (const int*)d_in[1];  // (2, E): src row then dst row
  const float* W1 = (const float*)d_in[2];
  const float* root1 = (const float*)d_in[3];
  const float* b1 = (const float*)d_in[4];
  const float* W2 = (const float*)d_in[5];
  const float* root2 = (const float*)d_in[6];
  const float* b2v = (const float*)d_in[7];
  float* out = (float*)d_out;

  const int* src = ei;
  const int* dstp = ei + NEDGE;

  // workspace layout (all 4B elems), ~32.8 MB total:
  // [rowptr N+4][cursor N][bsum 512][col E][xw1 16N (reused as agg2)]
  // [xr1 16N][h 16N]
  int* rowptr = (int*)d_ws;
  int* cursor = rowptr + (N_NODES + 4);
  int* bsum = cursor + N_NODES;
  int* col = bsum + 512;
  float* xw1 = (float*)(col + NEDGE);
  float* xr1 = xw1 + 16 * N_NODES;
  float* h = xr1 + 16 * N_NODES;
  float* agg2 = xw1;  // xw1 dead after gather1

  // zero histogram counts (cursor doubles as cnt)
  hipMemsetAsync(cursor, 0, (size_t)N_NODES * sizeof(int), stream);

  proj1_kernel<<<N_NODES / 8, 256, 0, stream>>>(x, W1, root1, xw1, xr1);
  hist_kernel<<<(NEDGE + 255) / 256, 256, 0, stream>>>(dstp, cursor);
  scanA_kernel<<<NB_SCAN, 256, 0, stream>>>(cursor, rowptr, bsum);
  scanB_kernel<<<1, 512, 0, stream>>>(bsum);
  scanC_kernel<<<NB_SCAN, 256, 0, stream>>>(rowptr, cursor, bsum);
  fill_kernel<<<(NEDGE + 255) / 256, 256, 0, stream>>>(src, dstp, cursor, col);
  gather1_kernel<<<(N_NODES * HID) / 256, 256, 0, stream>>>(rowptr, col, xw1,
                                                            xr1, b1, h);
  gather2_kernel<<<(N_NODES * HID) / 256, 256, 0, stream>>>(rowptr, col, h,
                                                            agg2);
  out_kernel<<<(N_NODES + 255) / 256, 256, 0, stream>>>(h, agg2, rowptr, W2,
                                                        root2, b2v, out);
}